// Round 3
// baseline (234.029 us; speedup 1.0000x reference)
//
#include <hip/hip_runtime.h>

#define BATCH 2
#define L_SEQ 2048
#define DI 2048
#define NROW (BATCH * L_SEQ)   // 4096
#define E_DIM 96
#define RNK 64                 // DT_RANK
#define NST 16                 // D_STATE
#define CL 32                  // chunk length
#define NCH 64                 // chunks
#define G 4                    // chunks per group (block-serial)
#define NG (NCH / G)           // 16 groups
#define SPLITK 8               // K1 split-K factor
#define KSL (DI / SPLITK)      // 256 k per split

// ---------------- workspace layout (floats) ----------------
// xdbl  : [NROW][96]                               393216
// partials : [SPLITK][NROW][96]  3145728  (K1 -> reduce, then dead)
//   hloc : [B][NG][NST][DI]      1048576  (overlays partials; C -> S2)
//   dsum : [B][NG][DI]             65536  (overlays partials; C -> S2)
// hent  : [B][NG][NST][DI]       1048576  (S2 -> S3), after partials
#define WS_XDBL 0
#define WS_PART 393216
#define WS_HLOC 393216
#define WS_DSUM (393216 + 1048576)
#define WS_HENT (393216 + 3145728)

__device__ __forceinline__ float softplusf(float z) {
    return fmaxf(z, 0.f) + __logf(1.f + __expf(-fabsf(z)));
}

// raw barrier: LDS-visibility only (lgkmcnt), does NOT drain vmcnt.
__device__ __forceinline__ void barrier_lds() {
    asm volatile("s_waitcnt lgkmcnt(0)" ::: "memory");
    __builtin_amdgcn_s_barrier();
}

// ===== K1a: partial[s] = x[:, ksl] @ W^T slice =====
// 256 threads, tile M=64 x N=96, k-step 32, KSL=256. grid (64, 8).
__global__ __launch_bounds__(256) void gemm_xproj_part(const float* __restrict__ x,
                                                       const float* __restrict__ Wx,
                                                       float* __restrict__ part) {
    __shared__ float xs[32][68];    // [k][row], pitch 272B
    __shared__ float wsh[32][100];  // [k][e],  pitch 400B
    const int tid = threadIdx.x;
    const int r0 = blockIdx.x * 64;
    const int kbase0 = blockIdx.y * KSL;
    const int rg = tid >> 4;   // 16 groups of 4 rows
    const int cg = tid & 15;   // 16 groups of 6 cols

    float acc[4][6];
#pragma unroll
    for (int i = 0; i < 4; i++)
#pragma unroll
        for (int j = 0; j < 6; j++) acc[i][j] = 0.f;

    for (int kt = 0; kt < KSL / 32; kt++) {
        const int kb = kbase0 + kt * 32;
#pragma unroll
        for (int rep = 0; rep < 2; rep++) {
            int i = rep * 256 + tid;   // 0..511
            int row = i >> 3;          // 0..63
            int kq = i & 7;
            float4 v = *(const float4*)&x[(long)(r0 + row) * DI + kb + kq * 4];
            xs[kq * 4 + 0][row] = v.x;
            xs[kq * 4 + 1][row] = v.y;
            xs[kq * 4 + 2][row] = v.z;
            xs[kq * 4 + 3][row] = v.w;
        }
#pragma unroll
        for (int rep = 0; rep < 3; rep++) {
            int i = rep * 256 + tid;   // 0..767
            int e = i >> 3;            // 0..95
            int kq = i & 7;
            float4 v = *(const float4*)&Wx[(long)e * DI + kb + kq * 4];
            wsh[kq * 4 + 0][e] = v.x;
            wsh[kq * 4 + 1][e] = v.y;
            wsh[kq * 4 + 2][e] = v.z;
            wsh[kq * 4 + 3][e] = v.w;
        }
        __syncthreads();
#pragma unroll 8
        for (int k = 0; k < 32; k++) {
            float xr[4], wr[6];
#pragma unroll
            for (int i = 0; i < 4; i++) xr[i] = xs[k][rg * 4 + i];
#pragma unroll
            for (int j = 0; j < 6; j++) wr[j] = wsh[k][cg * 6 + j];
#pragma unroll
            for (int i = 0; i < 4; i++)
#pragma unroll
                for (int j = 0; j < 6; j++) acc[i][j] = fmaf(xr[i], wr[j], acc[i][j]);
        }
        __syncthreads();
    }
    const long sbase = (long)blockIdx.y * NROW * E_DIM;
#pragma unroll
    for (int i = 0; i < 4; i++) {
        long rowb = sbase + (long)(r0 + rg * 4 + i) * E_DIM + cg * 6;
#pragma unroll
        for (int j = 0; j < 6; j++) part[rowb + j] = acc[i][j];
    }
}

// ===== K1b: xdbl = sum over splits =====
__global__ __launch_bounds__(256) void xproj_reduce(const float* __restrict__ part,
                                                    float* __restrict__ xdbl) {
    const int i4 = blockIdx.x * 256 + threadIdx.x;   // 98304 float4 outputs
    const float4* p4 = (const float4*)part;
    float4 s = p4[i4];
#pragma unroll
    for (int sp = 1; sp < SPLITK; sp++) {
        float4 v = p4[(long)sp * (NROW * E_DIM / 4) + i4];
        s.x += v.x; s.y += v.y; s.z += v.z; s.w += v.w;
    }
    ((float4*)xdbl)[i4] = s;
}

// ===== C: fused delta-GEMM + group-local scan (G=4 chunks per block) =====
// 512 threads, grid (DI/256, NG, BATCH) = 256 blocks, 1 block/CU (~155KB LDS).
// Wdt staged ONCE per block (full K=64). Per chunk: {x->reg prefetch | GEMM |
// stage x->LDS + epilogue->dtt | scan}. h carries across the 4 chunks; the
// n-dimension is split across thread halves (h[8] each). Raw lgkm barriers.
#define PWC 260   // wt pitch (floats), 16B-aligned rows
#define PDC 36    // dlb pitch
__global__ __launch_bounds__(512) void gemm_dt_scan(const float* __restrict__ x,
                                                    const float* __restrict__ xdbl,
                                                    const float* __restrict__ Wdt,
                                                    const float* __restrict__ b_dt,
                                                    const float* __restrict__ A_log,
                                                    float* __restrict__ delta,
                                                    float* __restrict__ hloc,
                                                    float* __restrict__ dsumb) {
    __shared__ float wt[RNK * PWC];       // 66560 B  Wdt [k][col], whole K
    __shared__ float dlb[2][RNK * PDC];   // 2x9216 B dlt [k][row], dbuf
    __shared__ float dtt[CL * 256];       // 32768 B  delta tile [l][d]
    __shared__ float xsh[CL * 256];       // 32768 B  x tile [l][d]
    __shared__ float bsm[G * CL * NST];   // 8192 B   B rows for whole group
    const int tid = threadIdx.x;
    const int d0 = blockIdx.x * 256;
    const int g = blockIdx.y;
    const int b = blockIdx.z;
    const int row0 = b * L_SEQ + g * (G * CL);
    const int dcol = tid & 255;
    const int d = d0 + dcol;
    const int half = tid >> 8;     // n-split: states half*8 .. half*8+7
    const int rg = tid >> 6;       // 8 row-groups of 4 (wave-uniform)
    const int cg = tid & 63;       // 64 col-groups of 4

    // ---- issue global loads: staging first, then params ----
    float4 wv[8];
#pragma unroll
    for (int rep = 0; rep < 8; rep++) {
        int i = rep * 512 + tid;           // 0..4095
        int col = i >> 4, kq = i & 15;
        wv[rep] = *(const float4*)&Wdt[(long)(d0 + col) * RNK + kq * 4];
    }
    float4 bv;
    { int r = tid >> 2, q = tid & 3;       // 512 f4 = 128 rows x 16
      bv = *(const float4*)&xdbl[(long)(row0 + r) * E_DIM + 64 + q * 4]; }
    float4 dv0;
    { int r = tid >> 4, kq = tid & 15;     // 512 f4 = 32 rows x 64 k
      dv0 = *(const float4*)&xdbl[(long)(row0 + r) * E_DIM + kq * 4]; }
    float4 av0 = *(const float4*)&A_log[(long)d * NST + half * 8];
    float4 av1 = *(const float4*)&A_log[(long)d * NST + half * 8 + 4];
    float4 bb  = *(const float4*)&b_dt[d0 + cg * 4];

    // ---- LDS writes (compiler inserts counted vmcnt waits) ----
#pragma unroll
    for (int rep = 0; rep < 8; rep++) {
        int i = rep * 512 + tid;
        int col = i >> 4, kq = i & 15;
        wt[(kq * 4 + 0) * PWC + col] = wv[rep].x;
        wt[(kq * 4 + 1) * PWC + col] = wv[rep].y;
        wt[(kq * 4 + 2) * PWC + col] = wv[rep].z;
        wt[(kq * 4 + 3) * PWC + col] = wv[rep].w;
    }
    { int r = tid >> 2, q = tid & 3;
      *(float4*)&bsm[r * NST + q * 4] = bv; }
    { int r = tid >> 4, kq = tid & 15;
      dlb[0][(kq * 4 + 0) * PDC + r] = dv0.x;
      dlb[0][(kq * 4 + 1) * PDC + r] = dv0.y;
      dlb[0][(kq * 4 + 2) * PDC + r] = dv0.z;
      dlb[0][(kq * 4 + 3) * PDC + r] = dv0.w; }

    float A[8];
    A[0] = -__expf(av0.x); A[1] = -__expf(av0.y);
    A[2] = -__expf(av0.z); A[3] = -__expf(av0.w);
    A[4] = -__expf(av1.x); A[5] = -__expf(av1.y);
    A[6] = -__expf(av1.z); A[7] = -__expf(av1.w);
    float h[8];
#pragma unroll
    for (int n = 0; n < 8; n++) h[n] = 0.f;
    float dsum = 0.f;

    barrier_lds();

    for (int cc = 0; cc < G; cc++) {
        const int cur = cc & 1;
        const int rowc = row0 + cc * CL;
        // prefetch x tile for THIS chunk (lands under the GEMM) + next dlt
        float4 xq[4];
#pragma unroll
        for (int rep = 0; rep < 4; rep++) {
            int i = rep * 512 + tid;       // 2048 f4 = 32 l x 64 f4
            int r = i >> 6, dq = i & 63;
            xq[rep] = *(const float4*)&x[(long)(rowc + r) * DI + d0 + dq * 4];
        }
        float4 dvn;
        if (cc < G - 1) {
            int r = tid >> 4, kq = tid & 15;
            dvn = *(const float4*)&xdbl[(long)(rowc + CL + r) * E_DIM + kq * 4];
        }
        // GEMM 32x256, full K=64
        float acc[4][4];
#pragma unroll
        for (int i = 0; i < 4; i++)
#pragma unroll
            for (int j = 0; j < 4; j++) acc[i][j] = 0.f;
#pragma unroll 8
        for (int k = 0; k < RNK; k++) {
            float4 xa = *(const float4*)&dlb[cur][k * PDC + rg * 4];   // broadcast
            float4 wr4 = *(const float4*)&wt[k * PWC + cg * 4];
            float xr[4] = {xa.x, xa.y, xa.z, xa.w};
            float wr[4] = {wr4.x, wr4.y, wr4.z, wr4.w};
#pragma unroll
            for (int i = 0; i < 4; i++)
#pragma unroll
                for (int j = 0; j < 4; j++) acc[i][j] = fmaf(xr[i], wr[j], acc[i][j]);
        }
        // stage next chunk's dlt into the other buffer (read after 2 barriers)
        if (cc < G - 1) {
            int r = tid >> 4, kq = tid & 15;
            dlb[cur ^ 1][(kq * 4 + 0) * PDC + r] = dvn.x;
            dlb[cur ^ 1][(kq * 4 + 1) * PDC + r] = dvn.y;
            dlb[cur ^ 1][(kq * 4 + 2) * PDC + r] = dvn.z;
            dlb[cur ^ 1][(kq * 4 + 3) * PDC + r] = dvn.w;
        }
        barrier_lds();   // all waves done scan(cc-1): dtt/xsh reusable
        // stage x tile
#pragma unroll
        for (int rep = 0; rep < 4; rep++) {
            int i = rep * 512 + tid;
            int r = i >> 6, dq = i & 63;
            *(float4*)&xsh[r * 256 + dq * 4] = xq[rep];
        }
        // epilogue: bias + softplus -> delta (global, fire-and-forget) + dtt
#pragma unroll
        for (int i = 0; i < 4; i++) {
            float4 o;
            o.x = softplusf(acc[i][0] + bb.x);
            o.y = softplusf(acc[i][1] + bb.y);
            o.z = softplusf(acc[i][2] + bb.z);
            o.w = softplusf(acc[i][3] + bb.w);
            *(float4*)&delta[(long)(rowc + rg * 4 + i) * DI + d0 + cg * 4] = o;
            *(float4*)&dtt[(rg * 4 + i) * 256 + cg * 4] = o;
        }
        barrier_lds();   // dtt/xsh visible; dlb[nxt] staged
        // scan this chunk (h carries across chunks)
        for (int ll = 0; ll < CL; ll++) {
            float dc = dtt[ll * 256 + dcol];
            float xc = xsh[ll * 256 + dcol];
            float du = dc * xc;
            float4 v0 = *(const float4*)&bsm[(cc * CL + ll) * NST + half * 8];
            float4 v1 = *(const float4*)&bsm[(cc * CL + ll) * NST + half * 8 + 4];
            h[0] = fmaf(__expf(dc * A[0]), h[0], du * v0.x);
            h[1] = fmaf(__expf(dc * A[1]), h[1], du * v0.y);
            h[2] = fmaf(__expf(dc * A[2]), h[2], du * v0.z);
            h[3] = fmaf(__expf(dc * A[3]), h[3], du * v0.w);
            h[4] = fmaf(__expf(dc * A[4]), h[4], du * v1.x);
            h[5] = fmaf(__expf(dc * A[5]), h[5], du * v1.y);
            h[6] = fmaf(__expf(dc * A[6]), h[6], du * v1.z);
            h[7] = fmaf(__expf(dc * A[7]), h[7], du * v1.w);
            dsum += dc;
        }
    }
    // hloc layout [b][g][n][d]: coalesced stores (and coalesced S2/S3 reads)
    const long gb = (long)(b * NG + g);
#pragma unroll
    for (int j = 0; j < 8; j++)
        hloc[(gb * NST + half * 8 + j) * DI + d] = h[j];
    if (half == 0) dsumb[gb * DI + d] = dsum;
}

// ===== S2: prefix over 16 chunk-groups -> entry states =====
__global__ __launch_bounds__(256) void scan_prefix(const float* __restrict__ A_log,
                                                   const float* __restrict__ hloc,
                                                   const float* __restrict__ dsumb,
                                                   float* __restrict__ hent) {
    const int gi = blockIdx.x * 256 + threadIdx.x;   // 65536 items, d fastest
    const int d = gi & (DI - 1);
    const int n = (gi >> 11) & 15;
    const int b = gi >> 15;
    const float An = -__expf(A_log[(long)d * NST + n]);
    float hl[NG], dsv[NG];
#pragma unroll
    for (int gg = 0; gg < NG; gg++) {
        hl[gg]  = hloc[((long)(b * NG + gg) * NST + n) * DI + d];
        dsv[gg] = dsumb[(long)(b * NG + gg) * DI + d];
    }
    float e[NG];
#pragma unroll
    for (int gg = 0; gg < NG; gg++) e[gg] = __expf(An * dsv[gg]);
    float hc = 0.f;
#pragma unroll
    for (int gg = 0; gg < NG; gg++) {
        hent[((long)(b * NG + gg) * NST + n) * DI + d] = hc;   // group entry
        hc = fmaf(e[gg], hc, hl[gg]);                          // group exit
    }
}

// ===== S3: output pass, G=4 chunks per block, x/delta staged via reg->LDS =====
// 256 threads, grid (DI/256, NG, BATCH) = 256 blocks, ~80KB LDS.
__global__ __launch_bounds__(256) void scan_out(const float* __restrict__ x,
                                                const float* __restrict__ xdbl,
                                                const float* __restrict__ A_log,
                                                const float* __restrict__ Dp,
                                                const float* __restrict__ hent,
                                                float* __restrict__ out) {
    __shared__ float xsh[CL * 256];       // 32KB
    __shared__ float dsh[CL * 256];       // 32KB (delta, currently in `out`)
    __shared__ float bsm[G * CL * NST];   // 8KB
    __shared__ float csm[G * CL * NST];   // 8KB
    const int tid = threadIdx.x;
    const int d0 = blockIdx.x * 256;
    const int g = blockIdx.y;
    const int b = blockIdx.z;
    const int row0 = b * L_SEQ + g * (G * CL);
    const int d = d0 + tid;

    // B/C staging for whole group: 512 f4 each, 2/thread
    float4 bq[2], cq[2];
#pragma unroll
    for (int rep = 0; rep < 2; rep++) {
        int i = rep * 256 + tid, r = i >> 2, q = i & 3;
        bq[rep] = *(const float4*)&xdbl[(long)(row0 + r) * E_DIM + 64 + q * 4];
        cq[rep] = *(const float4*)&xdbl[(long)(row0 + r) * E_DIM + 80 + q * 4];
    }
    // params
    float4 av[4];
#pragma unroll
    for (int q = 0; q < 4; q++)
        av[q] = *(const float4*)&A_log[(long)d * NST + q * 4];
    const long gb = (long)(b * NG + g);
    float hv[16];
#pragma unroll
    for (int n = 0; n < 16; n++)
        hv[n] = hent[(gb * NST + n) * DI + d];
    const float Dd = Dp[d];
    // chunk-0 x/delta tiles: 8 f4 each
    float4 xq[8], dq[8];
#pragma unroll
    for (int rep = 0; rep < 8; rep++) {
        int i = rep * 256 + tid, r = i >> 6, dqc = i & 63;
        xq[rep] = *(const float4*)&x[(long)(row0 + r) * DI + d0 + dqc * 4];
        dq[rep] = *(const float4*)&out[(long)(row0 + r) * DI + d0 + dqc * 4];
    }

#pragma unroll
    for (int rep = 0; rep < 2; rep++) {
        int i = rep * 256 + tid, r = i >> 2, q = i & 3;
        *(float4*)&bsm[r * NST + q * 4] = bq[rep];
        *(float4*)&csm[r * NST + q * 4] = cq[rep];
    }
#pragma unroll
    for (int rep = 0; rep < 8; rep++) {
        int i = rep * 256 + tid, r = i >> 6, dqc = i & 63;
        *(float4*)&xsh[r * 256 + dqc * 4] = xq[rep];
        *(float4*)&dsh[r * 256 + dqc * 4] = dq[rep];
    }

    float A[16], h[16];
#pragma unroll
    for (int q = 0; q < 4; q++) {
        A[q * 4 + 0] = -__expf(av[q].x);
        A[q * 4 + 1] = -__expf(av[q].y);
        A[q * 4 + 2] = -__expf(av[q].z);
        A[q * 4 + 3] = -__expf(av[q].w);
    }
#pragma unroll
    for (int n = 0; n < 16; n++) h[n] = hv[n];

    barrier_lds();

    for (int cc = 0; cc < G; cc++) {
        const int rowc = row0 + cc * CL;
        // prefetch next chunk's tiles (land under this chunk's scan)
        float4 xn[8], dn[8];
        if (cc < G - 1) {
#pragma unroll
            for (int rep = 0; rep < 8; rep++) {
                int i = rep * 256 + tid, r = i >> 6, dqc = i & 63;
                xn[rep] = *(const float4*)&x[(long)(rowc + CL + r) * DI + d0 + dqc * 4];
                dn[rep] = *(const float4*)&out[(long)(rowc + CL + r) * DI + d0 + dqc * 4];
            }
        }
        long idx = (long)rowc * DI + d;
        for (int ll = 0; ll < CL; ll++) {
            float dc = dsh[ll * 256 + tid];
            float xc = xsh[ll * 256 + tid];
            float du = dc * xc;
            float y = 0.f;
#pragma unroll
            for (int q = 0; q < 4; q++) {
                float4 v = *(const float4*)&bsm[(cc * CL + ll) * NST + q * 4];
                float4 w = *(const float4*)&csm[(cc * CL + ll) * NST + q * 4];
                float e0 = __expf(dc * A[q * 4 + 0]);
                float e1 = __expf(dc * A[q * 4 + 1]);
                float e2 = __expf(dc * A[q * 4 + 2]);
                float e3 = __expf(dc * A[q * 4 + 3]);
                h[q * 4 + 0] = fmaf(e0, h[q * 4 + 0], du * v.x);
                h[q * 4 + 1] = fmaf(e1, h[q * 4 + 1], du * v.y);
                h[q * 4 + 2] = fmaf(e2, h[q * 4 + 2], du * v.z);
                h[q * 4 + 3] = fmaf(e3, h[q * 4 + 3], du * v.w);
                y = fmaf(h[q * 4 + 0], w.x, y);
                y = fmaf(h[q * 4 + 1], w.y, y);
                y = fmaf(h[q * 4 + 2], w.z, y);
                y = fmaf(h[q * 4 + 3], w.w, y);
            }
            out[idx] = fmaf(xc, Dd, y);
            idx += DI;
        }
        barrier_lds();   // all waves done with xsh/dsh(cc)
        if (cc < G - 1) {
#pragma unroll
            for (int rep = 0; rep < 8; rep++) {
                int i = rep * 256 + tid, r = i >> 6, dqc = i & 63;
                *(float4*)&xsh[r * 256 + dqc * 4] = xn[rep];
                *(float4*)&dsh[r * 256 + dqc * 4] = dn[rep];
            }
            barrier_lds();   // staged tiles visible
        }
    }
}

extern "C" void kernel_launch(void* const* d_in, const int* in_sizes, int n_in,
                              void* d_out, int out_size, void* d_ws, size_t ws_size,
                              hipStream_t stream) {
    const float* x    = (const float*)d_in[0];
    const float* Wx   = (const float*)d_in[1];
    const float* Wdt  = (const float*)d_in[2];
    const float* bdt  = (const float*)d_in[3];
    const float* Alog = (const float*)d_in[4];
    const float* Dp   = (const float*)d_in[5];
    float* out = (float*)d_out;
    float* ws = (float*)d_ws;
    float* xdbl  = ws + WS_XDBL;
    float* partb = ws + WS_PART;
    float* hloc  = ws + WS_HLOC;   // overlays partb (disjoint lifetime)
    float* dsumb = ws + WS_DSUM;
    float* hent  = ws + WS_HENT;

    gemm_xproj_part<<<dim3(NROW / 64, SPLITK), 256, 0, stream>>>(x, Wx, partb);
    xproj_reduce<<<dim3(NROW * E_DIM / 4 / 256), 256, 0, stream>>>(partb, xdbl);
    gemm_dt_scan<<<dim3(DI / 256, NG, BATCH), 512, 0, stream>>>(x, xdbl, Wdt, bdt, Alog,
                                                                out, hloc, dsumb);
    scan_prefix<<<dim3(BATCH * DI * NST / 256), 256, 0, stream>>>(Alog, hloc, dsumb, hent);
    scan_out<<<dim3(DI / 256, NG, BATCH), 256, 0, stream>>>(x, xdbl, Alog, Dp, hent, out);
}

// Round 4
// 188.457 us; speedup vs baseline: 1.2418x; 1.2418x over previous
//
#include <hip/hip_runtime.h>

#define BATCH 2
#define L_SEQ 2048
#define DI 2048
#define NROW (BATCH * L_SEQ)   // 4096
#define E_DIM 96
#define RNK 64                 // DT_RANK
#define NST 16                 // D_STATE
#define NCH 64                 // chunks
#define CL 32                  // chunk length (NCH*CL == L_SEQ)
#define SPLITK 16              // K1 split-K factor
#define KSL (DI / SPLITK)      // 128 k per split

// ---------------- workspace layout (floats) ----------------
// xdbl  : [NROW][96]                               393216
// partials : [SPLITK][NROW][96]  6291456  (K1 -> reduce, then dead)
//   hloc : [B][NCH][NST][DI]     2097152*2=4194304 (overlays partials; C -> S2)
//   dsum : [B][NCH][DI]           262144  (overlays partials; C -> S2)
// hent  : [B][NCH][NST][DI]      4194304  (S2 -> S3), after partials
//   WdtT : [RNK][DI]              131072  (overlays hent head; K1b -> C, dead before S2)
#define WS_XDBL 0
#define WS_PART 393216
#define WS_HLOC 393216
#define WS_DSUM (393216 + 4194304)
#define WS_HENT (393216 + 6291456)
#define WS_WDTT (393216 + 6291456)   // overlays hent: C reads it before S2 writes hent

__device__ __forceinline__ float softplusf(float z) {
    return fmaxf(z, 0.f) + __logf(1.f + __expf(-fabsf(z)));
}

// raw barrier: LDS-visibility only (lgkmcnt), does NOT drain vmcnt.
__device__ __forceinline__ void barrier_lds() {
    asm volatile("s_waitcnt lgkmcnt(0)" ::: "memory");
    __builtin_amdgcn_s_barrier();
}

// ===== K1a: partial[s] = x[:, ksl] @ W^T slice =====
// 256 threads, tile M=64 x N=96, k-step 32, KSL=128. grid (64, 16).
__global__ __launch_bounds__(256) void gemm_xproj_part(const float* __restrict__ x,
                                                       const float* __restrict__ Wx,
                                                       float* __restrict__ part) {
    __shared__ float xs[32][68];    // [k][row], pitch 272B
    __shared__ float wsh[32][100];  // [k][e],  pitch 400B
    const int tid = threadIdx.x;
    const int r0 = blockIdx.x * 64;
    const int kbase0 = blockIdx.y * KSL;
    const int rg = tid >> 4;   // 16 groups of 4 rows
    const int cg = tid & 15;   // 16 groups of 6 cols

    float acc[4][6];
#pragma unroll
    for (int i = 0; i < 4; i++)
#pragma unroll
        for (int j = 0; j < 6; j++) acc[i][j] = 0.f;

    for (int kt = 0; kt < KSL / 32; kt++) {
        const int kb = kbase0 + kt * 32;
#pragma unroll
        for (int rep = 0; rep < 2; rep++) {
            int i = rep * 256 + tid;   // 0..511
            int row = i >> 3;          // 0..63
            int kq = i & 7;
            float4 v = *(const float4*)&x[(long)(r0 + row) * DI + kb + kq * 4];
            xs[kq * 4 + 0][row] = v.x;
            xs[kq * 4 + 1][row] = v.y;
            xs[kq * 4 + 2][row] = v.z;
            xs[kq * 4 + 3][row] = v.w;
        }
#pragma unroll
        for (int rep = 0; rep < 3; rep++) {
            int i = rep * 256 + tid;   // 0..767
            int e = i >> 3;            // 0..95
            int kq = i & 7;
            float4 v = *(const float4*)&Wx[(long)e * DI + kb + kq * 4];
            wsh[kq * 4 + 0][e] = v.x;
            wsh[kq * 4 + 1][e] = v.y;
            wsh[kq * 4 + 2][e] = v.z;
            wsh[kq * 4 + 3][e] = v.w;
        }
        __syncthreads();
#pragma unroll 8
        for (int k = 0; k < 32; k++) {
            float xr[4], wr[6];
#pragma unroll
            for (int i = 0; i < 4; i++) xr[i] = xs[k][rg * 4 + i];
#pragma unroll
            for (int j = 0; j < 6; j++) wr[j] = wsh[k][cg * 6 + j];
#pragma unroll
            for (int i = 0; i < 4; i++)
#pragma unroll
                for (int j = 0; j < 6; j++) acc[i][j] = fmaf(xr[i], wr[j], acc[i][j]);
        }
        __syncthreads();
    }
    const long sbase = (long)blockIdx.y * NROW * E_DIM;
#pragma unroll
    for (int i = 0; i < 4; i++) {
        long rowb = sbase + (long)(r0 + rg * 4 + i) * E_DIM + cg * 6;
#pragma unroll
        for (int j = 0; j < 6; j++) part[rowb + j] = acc[i][j];
    }
}

// ===== K1b: xdbl = sum over splits  +  WdtT transpose (extra blocks) =====
// grid 384 (reduce) + 128 (transpose) blocks; transpose rides the idle CUs.
__global__ __launch_bounds__(256) void xproj_reduce_wt(const float* __restrict__ part,
                                                       float* __restrict__ xdbl,
                                                       const float* __restrict__ Wdt,
                                                       float* __restrict__ wdtT) {
    if (blockIdx.x < 384) {
        const int i4 = blockIdx.x * 256 + threadIdx.x;   // 98304 float4 outputs
        const float4* p4 = (const float4*)part;
        float4 s = p4[i4];
#pragma unroll
        for (int sp = 1; sp < SPLITK; sp++) {
            float4 v = p4[(long)sp * (NROW * E_DIM / 4) + i4];
            s.x += v.x; s.y += v.y; s.z += v.z; s.w += v.w;
        }
        ((float4*)xdbl)[i4] = s;
    } else {
        // WdtT[r][d] = Wdt[d][r]; coalesced writes, scattered reads (L2-absorbed)
        const int t = (blockIdx.x - 384) * 256 + threadIdx.x;   // 0..32767
        const int base = t * 4;
        const int r = base >> 11;         // /DI
        const int d4 = base & (DI - 1);
        float4 o;
        o.x = Wdt[(long)(d4 + 0) * RNK + r];
        o.y = Wdt[(long)(d4 + 1) * RNK + r];
        o.z = Wdt[(long)(d4 + 2) * RNK + r];
        o.w = Wdt[(long)(d4 + 3) * RNK + r];
        *(float4*)&wdtT[base] = o;
    }
}

// ===== C: fused delta-GEMM + chunk-local scan =====
// grid (DI/256, NCH, BATCH), 256 threads, ~40KB LDS (4 blocks/CU).
// wt staged from WdtT with float4->ds_write_b128 (conflict-free, no transpose).
// Scan uses 1 exp + power chain when A[n] == (n+1)*A[0] (true for this A_log).
#define PW 260   // wt pitch (floats), 16B-aligned rows
#define PD 36    // dlb pitch
__global__ __launch_bounds__(256) void gemm_dt_scan(const float* __restrict__ x,
                                                    const float* __restrict__ xdbl,
                                                    const float* __restrict__ wdtT,
                                                    const float* __restrict__ b_dt,
                                                    const float* __restrict__ A_log,
                                                    float* __restrict__ delta,
                                                    float* __restrict__ hloc,
                                                    float* __restrict__ dsumb) {
    __shared__ float region[32 * PW + 32 * PD];   // GEMM staging; dtt overlay
    __shared__ float bsm[CL * NST];               // 2 KB B tile
    float* wt  = region;                 // [32][PW]  Wdt^T staging [k][col]
    float* dlb = region + 32 * PW;       // [32][PD]  dlt staging [k][row]
    float* dtt = region;                 // [32][256] delta tile (overlay, after GEMM)

    const int tid = threadIdx.x;
    const int d0 = blockIdx.x * 256;
    const int c = blockIdx.y;
    const int b = blockIdx.z;
    const int row0 = b * L_SEQ + c * CL;
    const int d = d0 + tid;
    const int rg = tid >> 6;   // 4 groups of 8 rows (wave-uniform)
    const int cg = tid & 63;   // 64 groups of 4 cols

    // B tile (rows row0..row0+31, xdbl cols 64..79)
    if (tid < 128) {
        int r = tid >> 2, q = tid & 3;
        ((float4*)bsm)[tid] = *(const float4*)&xdbl[(long)(row0 + r) * E_DIM + 64 + q * 4];
    }

    float acc[8][4];
#pragma unroll
    for (int i = 0; i < 8; i++)
#pragma unroll
        for (int j = 0; j < 4; j++) acc[i][j] = 0.f;

    float xv[CL];     // x column prefetch (registers)
    float4 av[4];     // raw A_log (exp applied later)

#pragma unroll
    for (int kt = 0; kt < 2; kt++) {
        const int kb = kt * 32;
        // wt tile from WdtT: 32k x 256 cols = 2048 f4, 8/thread, b128 writes
#pragma unroll
        for (int rep = 0; rep < 8; rep++) {
            int i = rep * 256 + tid;
            int k = i >> 6, c4 = i & 63;
            float4 v = *(const float4*)&wdtT[(long)(kb + k) * DI + d0 + c4 * 4];
            *(float4*)&wt[k * PW + c4 * 4] = v;
        }
        // dlt tile: 32 rows x 32 k = 256 float4, 1/thread (small transpose)
        {
            int r = tid >> 3, kq = tid & 7;
            float4 v = *(const float4*)&xdbl[(long)(row0 + r) * E_DIM + kb + kq * 4];
            dlb[(kq * 4 + 0) * PD + r] = v.x;
            dlb[(kq * 4 + 1) * PD + r] = v.y;
            dlb[(kq * 4 + 2) * PD + r] = v.z;
            dlb[(kq * 4 + 3) * PD + r] = v.w;
        }
        if (kt == 0) {
            // x + A prefetch AFTER staging loads (FIFO vmcnt: staging waits
            // don't force these); they land under GEMM kt0/kt1.
#pragma unroll
            for (int ll = 0; ll < CL; ll++)
                xv[ll] = x[(long)(row0 + ll) * DI + d];
#pragma unroll
            for (int q = 0; q < 4; q++)
                av[q] = *(const float4*)&A_log[(long)d * NST + q * 4];
        }
        barrier_lds();
#pragma unroll 8
        for (int k = 0; k < 32; k++) {
            float4 xa = *(const float4*)&dlb[k * PD + rg * 8];       // broadcast
            float4 xb = *(const float4*)&dlb[k * PD + rg * 8 + 4];   // broadcast
            float4 wv4 = *(const float4*)&wt[k * PW + cg * 4];       // 16B-stride
            float xr[8] = {xa.x, xa.y, xa.z, xa.w, xb.x, xb.y, xb.z, xb.w};
            float wr[4] = {wv4.x, wv4.y, wv4.z, wv4.w};
#pragma unroll
            for (int i = 0; i < 8; i++)
#pragma unroll
                for (int j = 0; j < 4; j++) acc[i][j] = fmaf(xr[i], wr[j], acc[i][j]);
        }
        barrier_lds();   // protects staging overwrite (kt=1) / dtt overlay (epilogue)
    }

    // epilogue: bias + softplus -> global delta (fire-and-forget) + LDS delta tile
    float4 bb = *(const float4*)&b_dt[d0 + cg * 4];
#pragma unroll
    for (int i = 0; i < 8; i++) {
        int r = rg * 8 + i;
        float4 o;
        o.x = softplusf(acc[i][0] + bb.x);
        o.y = softplusf(acc[i][1] + bb.y);
        o.z = softplusf(acc[i][2] + bb.z);
        o.w = softplusf(acc[i][3] + bb.w);
        *(float4*)&delta[(long)(row0 + r) * DI + d0 + cg * 4] = o;
        *(float4*)&dtt[r * 256 + cg * 4] = o;
    }

    float A[16];
#pragma unroll
    for (int q = 0; q < 4; q++) {
        A[q * 4 + 0] = -__expf(av[q].x);
        A[q * 4 + 1] = -__expf(av[q].y);
        A[q * 4 + 2] = -__expf(av[q].z);
        A[q * 4 + 3] = -__expf(av[q].w);
    }
    const float A0 = A[0];
    bool fast = true;
#pragma unroll
    for (int n = 1; n < 16; n++)
        fast = fast && (fabsf(A[n] - (float)(n + 1) * A0) <= 1e-4f * (float)(n + 1));
    barrier_lds();   // dtt visible

    float h[16];
#pragma unroll
    for (int n = 0; n < 16; n++) h[n] = 0.f;
    float dsum = 0.f;
    if (fast) {
        for (int ll = 0; ll < CL; ll++) {
            float dc = dtt[ll * 256 + tid];
            float du = dc * xv[ll];
            float p1 = __expf(dc * A0);
            float p2 = p1 * p1, p3 = p2 * p1, p4 = p2 * p2, p5 = p3 * p2;
            float p6 = p3 * p3, p7 = p4 * p3, p8 = p4 * p4, p9 = p5 * p4;
            float p10 = p5 * p5, p11 = p6 * p5, p12 = p6 * p6, p13 = p7 * p6;
            float p14 = p7 * p7, p15 = p8 * p7, p16 = p8 * p8;
            float e_[16] = {p1, p2, p3, p4, p5, p6, p7, p8,
                            p9, p10, p11, p12, p13, p14, p15, p16};
#pragma unroll
            for (int q = 0; q < 4; q++) {
                float4 v = *(const float4*)&bsm[ll * NST + q * 4];   // broadcast
                h[q * 4 + 0] = fmaf(e_[q * 4 + 0], h[q * 4 + 0], du * v.x);
                h[q * 4 + 1] = fmaf(e_[q * 4 + 1], h[q * 4 + 1], du * v.y);
                h[q * 4 + 2] = fmaf(e_[q * 4 + 2], h[q * 4 + 2], du * v.z);
                h[q * 4 + 3] = fmaf(e_[q * 4 + 3], h[q * 4 + 3], du * v.w);
            }
            dsum += dc;
        }
    } else {
        for (int ll = 0; ll < CL; ll++) {
            float dc = dtt[ll * 256 + tid];
            float du = dc * xv[ll];
#pragma unroll
            for (int q = 0; q < 4; q++) {
                float4 v = *(const float4*)&bsm[ll * NST + q * 4];
                h[q * 4 + 0] = fmaf(__expf(dc * A[q * 4 + 0]), h[q * 4 + 0], du * v.x);
                h[q * 4 + 1] = fmaf(__expf(dc * A[q * 4 + 1]), h[q * 4 + 1], du * v.y);
                h[q * 4 + 2] = fmaf(__expf(dc * A[q * 4 + 2]), h[q * 4 + 2], du * v.z);
                h[q * 4 + 3] = fmaf(__expf(dc * A[q * 4 + 3]), h[q * 4 + 3], du * v.w);
            }
            dsum += dc;
        }
    }
    // hloc layout [b][c][n][d]: 16 coalesced scalar stores
    const long cb = (long)(b * NCH + c);
#pragma unroll
    for (int n = 0; n < 16; n++)
        hloc[(cb * NST + n) * DI + d] = h[n];
    dsumb[cb * DI + d] = dsum;
}

// ===== S2: prefix over chunks -> entry states (coalesced layout) =====
__global__ __launch_bounds__(256, 1) void scan_prefix(const float* __restrict__ A_log,
                                                      const float* __restrict__ hloc,
                                                      const float* __restrict__ dsumb,
                                                      float* __restrict__ hent) {
    const int g = blockIdx.x * 256 + threadIdx.x;   // 65536 items, d fastest
    const int d = g & (DI - 1);
    const int n = (g >> 11) & 15;
    const int b = g >> 15;
    const float An = -__expf(A_log[(long)d * NST + n]);
    float hl[NCH], dsv[NCH];
#pragma unroll
    for (int cc = 0; cc < NCH; cc++) {
        hl[cc]  = hloc[((long)(b * NCH + cc) * NST + n) * DI + d];
        dsv[cc] = dsumb[(long)(b * NCH + cc) * DI + d];
    }
    float e[NCH];
#pragma unroll
    for (int cc = 0; cc < NCH; cc++) e[cc] = __expf(An * dsv[cc]);
    float hc = 0.f;
#pragma unroll
    for (int cc = 0; cc < NCH; cc++) {
        hent[((long)(b * NCH + cc) * NST + n) * DI + d] = hc;   // entry state
        hc = fmaf(e[cc], hc, hl[cc]);                           // exit state
    }
}

// ===== S3: output pass — x/delta columns prefetched to REGISTERS =====
__global__ __launch_bounds__(256) void scan_out(const float* __restrict__ x,
                                                const float* __restrict__ xdbl,
                                                const float* __restrict__ A_log,
                                                const float* __restrict__ Dp,
                                                const float* __restrict__ hent,
                                                float* __restrict__ out) {
    __shared__ float bsm[CL * NST];
    __shared__ float csm[CL * NST];
    const int tid = threadIdx.x;
    const int d0 = blockIdx.x * 256;
    const int c = blockIdx.y;
    const int b = blockIdx.z;
    const int row0 = b * L_SEQ + c * CL;
    const int d = d0 + tid;

    {
        int i = tid & 127, r = i >> 2, q = i & 3;
        float4 v = *(const float4*)&xdbl[(long)(row0 + r) * E_DIM + 64 + ((tid >> 7) << 4) + q * 4];
        if (tid < 128) ((float4*)bsm)[i] = v;
        else           ((float4*)csm)[i] = v;
    }
    __syncthreads();   // only LDS staging outstanding; cheap drain

    // params first (oldest in vmcnt FIFO)
    float4 av[4];
#pragma unroll
    for (int q = 0; q < 4; q++)
        av[q] = *(const float4*)&A_log[(long)d * NST + q * 4];
    const long cb = (long)(b * NCH + c);
    float hv[16];
#pragma unroll
    for (int n = 0; n < 16; n++)
        hv[n] = hent[(cb * NST + n) * DI + d];
    const float Dd = Dp[d];

    // column prefetch: delta (in `out`) + x
    float dv[CL], xv[CL];
#pragma unroll
    for (int ll = 0; ll < CL; ll++) {
        dv[ll] = out[(long)(row0 + ll) * DI + d];
        xv[ll] = x[(long)(row0 + ll) * DI + d];
    }

    float A[16];
#pragma unroll
    for (int q = 0; q < 4; q++) {
        A[q * 4 + 0] = -__expf(av[q].x);
        A[q * 4 + 1] = -__expf(av[q].y);
        A[q * 4 + 2] = -__expf(av[q].z);
        A[q * 4 + 3] = -__expf(av[q].w);
    }
    const float A0 = A[0];
    bool fast = true;
#pragma unroll
    for (int n = 1; n < 16; n++)
        fast = fast && (fabsf(A[n] - (float)(n + 1) * A0) <= 1e-4f * (float)(n + 1));
    float h[16];
#pragma unroll
    for (int n = 0; n < 16; n++) h[n] = hv[n];

    long idx = (long)row0 * DI + d;
    if (fast) {
        for (int ll = 0; ll < CL; ll++) {
            float dc = dv[ll];
            float xc = xv[ll];
            float du = dc * xc;
            float p1 = __expf(dc * A0);
            float p2 = p1 * p1, p3 = p2 * p1, p4 = p2 * p2, p5 = p3 * p2;
            float p6 = p3 * p3, p7 = p4 * p3, p8 = p4 * p4, p9 = p5 * p4;
            float p10 = p5 * p5, p11 = p6 * p5, p12 = p6 * p6, p13 = p7 * p6;
            float p14 = p7 * p7, p15 = p8 * p7, p16 = p8 * p8;
            float e_[16] = {p1, p2, p3, p4, p5, p6, p7, p8,
                            p9, p10, p11, p12, p13, p14, p15, p16};
            float y = 0.f;
#pragma unroll
            for (int q = 0; q < 4; q++) {
                float4 v = *(const float4*)&bsm[ll * NST + q * 4];
                float4 w = *(const float4*)&csm[ll * NST + q * 4];
                h[q * 4 + 0] = fmaf(e_[q * 4 + 0], h[q * 4 + 0], du * v.x);
                h[q * 4 + 1] = fmaf(e_[q * 4 + 1], h[q * 4 + 1], du * v.y);
                h[q * 4 + 2] = fmaf(e_[q * 4 + 2], h[q * 4 + 2], du * v.z);
                h[q * 4 + 3] = fmaf(e_[q * 4 + 3], h[q * 4 + 3], du * v.w);
                y = fmaf(h[q * 4 + 0], w.x, y);
                y = fmaf(h[q * 4 + 1], w.y, y);
                y = fmaf(h[q * 4 + 2], w.z, y);
                y = fmaf(h[q * 4 + 3], w.w, y);
            }
            out[idx] = fmaf(xc, Dd, y);
            idx += DI;
        }
    } else {
        for (int ll = 0; ll < CL; ll++) {
            float dc = dv[ll];
            float xc = xv[ll];
            float du = dc * xc;
            float y = 0.f;
#pragma unroll
            for (int q = 0; q < 4; q++) {
                float4 v = *(const float4*)&bsm[ll * NST + q * 4];
                float4 w = *(const float4*)&csm[ll * NST + q * 4];
                float e0 = __expf(dc * A[q * 4 + 0]);
                float e1 = __expf(dc * A[q * 4 + 1]);
                float e2 = __expf(dc * A[q * 4 + 2]);
                float e3 = __expf(dc * A[q * 4 + 3]);
                h[q * 4 + 0] = fmaf(e0, h[q * 4 + 0], du * v.x);
                h[q * 4 + 1] = fmaf(e1, h[q * 4 + 1], du * v.y);
                h[q * 4 + 2] = fmaf(e2, h[q * 4 + 2], du * v.z);
                h[q * 4 + 3] = fmaf(e3, h[q * 4 + 3], du * v.w);
                y = fmaf(h[q * 4 + 0], w.x, y);
                y = fmaf(h[q * 4 + 1], w.y, y);
                y = fmaf(h[q * 4 + 2], w.z, y);
                y = fmaf(h[q * 4 + 3], w.w, y);
            }
            out[idx] = fmaf(xc, Dd, y);
            idx += DI;
        }
    }
}

extern "C" void kernel_launch(void* const* d_in, const int* in_sizes, int n_in,
                              void* d_out, int out_size, void* d_ws, size_t ws_size,
                              hipStream_t stream) {
    const float* x    = (const float*)d_in[0];
    const float* Wx   = (const float*)d_in[1];
    const float* Wdt  = (const float*)d_in[2];
    const float* bdt  = (const float*)d_in[3];
    const float* Alog = (const float*)d_in[4];
    const float* Dp   = (const float*)d_in[5];
    float* out = (float*)d_out;
    float* ws = (float*)d_ws;
    float* xdbl  = ws + WS_XDBL;
    float* partb = ws + WS_PART;
    float* hloc  = ws + WS_HLOC;   // overlays partb (disjoint lifetime)
    float* dsumb = ws + WS_DSUM;
    float* hent  = ws + WS_HENT;
    float* wdtT  = ws + WS_WDTT;   // overlays hent head (dead before S2 writes)

    gemm_xproj_part<<<dim3(NROW / 64, SPLITK), 256, 0, stream>>>(x, Wx, partb);
    xproj_reduce_wt<<<dim3(384 + 128), 256, 0, stream>>>(partb, xdbl, Wdt, wdtT);
    gemm_dt_scan<<<dim3(DI / 256, NCH, BATCH), 256, 0, stream>>>(x, xdbl, wdtT, bdt, Alog,
                                                                 out, hloc, dsumb);
    scan_prefix<<<dim3(BATCH * DI * NST / 256), 256, 0, stream>>>(Alog, hloc, dsumb, hent);
    scan_out<<<dim3(DI / 256, NCH, BATCH), 256, 0, stream>>>(x, xdbl, Alog, Dp, hent, out);
}